// Round 12
// baseline (113.299 us; speedup 1.0000x reference)
//
#include <hip/hip_runtime.h>
#include <math.h>

// StructureLoss — R12: x/t prefetch moved INTO stage-1's shadow.
// R11 post-mortem: nt-hint caused R10's regression; register-tails' -33 MB
// of requests converted to ~0 us -> not request-volume-bound at 16 waves/CU
// (main ~30 us = ~9.1 B/cyc/CU vs 10.2 copy ceiling). Residual slack is the
// unoverlapped x/t fetch between stage-1 and the barrier.
// R12: issue xg/tg right after the warm-up sum so the 4-step main loop +
// barrier cover their latency. Tails re-loaded from global (R7 style) to
// keep peak VGPR ~100 < 128 cap (register-tails + early x/t would spill).

#define IMG_H 512
#define IMG_W 512
#define NB    32
#define HW    (IMG_H * IMG_W)
#define RG    16              // output rows per block
#define NGRP  (IMG_H / RG)    // 32 row-groups per image
#define NTH   256
#define VST   576             // LDS row stride (floats); 512 + 16*4 skew

// skew +4 floats per 32-col chunk: chunk s occupies [36s, 36s+31], 16B-aligned
__device__ __forceinline__ int vidx(int c) { return c + 4 * (c >> 5); }

__device__ __forceinline__ float wave_reduce(float v) {
#pragma unroll
  for (int off = 32; off > 0; off >>= 1) v += __shfl_down(v, off, 64);
  return v;
}

__global__ __launch_bounds__(NTH, 4) void sloss_main(const float* __restrict__ x,
                                                     const float* __restrict__ t,
                                                     float* __restrict__ part) {
  __shared__ float vls[RG * VST];   // 16*576*4 = 36864 B -> 4 blocks/CU
  __shared__ float red[4][4];

  const int tid = threadIdx.x;
  // XCD swizzle: one image's 32 groups stay on one XCD -> halo rows L2-hit.
  const int xcd = blockIdx.x & 7;
  const int k   = blockIdx.x >> 3;        // 0..127
  const int img = (xcd << 2) | (k >> 5);  // 4 images per XCD
  const int grp = k & 31;
  const int r0  = grp * RG;
  const float* tb = t + (size_t)img * HW;
  const float* xb = x + (size_t)img * HW;

  // stage-2 thread mapping (needed early for the x/t prefetch)
  const int row = tid >> 4;                 // 0..15
  const int sub = tid & 15;                 // 0..15 (32-col chunk)
  const int c0  = sub * 32;
  const float* xr = xb + (size_t)(r0 + row) * IMG_W + c0;
  const float* tr = tb + (size_t)(r0 + row) * IMG_W + c0;
  float4 xg[8], tg[8];

  // ---- Stage 1: vertical 31-row running sums; thread owns cols 2t,2t+1 ----
  {
    const float2* tc2 = (const float2*)tb + tid;   // row stride = 256 float2
    const int li = vidx(2 * tid);
    float sx, sy;
    if (grp >= 1 && grp <= 30) {                   // interior: no row guards
      // warm-up rows r0-15..r0+14: one 30-load batch, summed immediately
      // (w dies here -> VGPR headroom for the early x/t prefetch below)
      {
        float2 w[30];
#pragma unroll
        for (int j = 0; j < 30; ++j) w[j] = tc2[(r0 - 15 + j) * 256];
        float ax = 0.f, ay = 0.f, bx2 = 0.f, by2 = 0.f, cx = 0.f, cy = 0.f;
#pragma unroll
        for (int j = 0; j < 10; ++j) { ax += w[j].x; ay += w[j].y; }
#pragma unroll
        for (int j = 10; j < 20; ++j) { bx2 += w[j].x; by2 += w[j].y; }
#pragma unroll
        for (int j = 20; j < 30; ++j) { cx += w[j].x; cy += w[j].y; }
        sx = ax + bx2 + cx; sy = ay + by2 + cy;
      }

      // ---- early x/t prefetch: latency covered by main loop + barrier ----
#pragma unroll
      for (int jc = 0; jc < 8; ++jc) {
        xg[jc] = *(const float4*)(xr + 4 * jc);
        tg[jc] = *(const float4*)(tr + 4 * jc);
      }

      // main loop: 4 rows/step, 4 head + 4 tail loads batched (R7 style)
#pragma unroll
      for (int c = 0; c < 4; ++c) {
        float2 hd[4], tl[4];
#pragma unroll
        for (int j = 0; j < 4; ++j) {
          hd[j] = tc2[(r0 + 4 * c + j + 15) * 256];
          tl[j] = tc2[(r0 + 4 * c + j - 15) * 256];
        }
#pragma unroll
        for (int j = 0; j < 4; ++j) {
          const int i = 4 * c + j;
          sx += hd[j].x; sy += hd[j].y;
          vls[i * VST + li] = sx; vls[i * VST + li + 1] = sy;
          sx -= tl[j].x; sy -= tl[j].y;
        }
      }
    } else {                                       // edge groups: guarded
      sx = 0.f; sy = 0.f;
#pragma unroll
      for (int kk = -15; kk < 15; ++kk) {
        int r = r0 + kk;
        if ((unsigned)r < IMG_H) { float2 v = tc2[r * 256]; sx += v.x; sy += v.y; }
      }
#pragma unroll
      for (int jc = 0; jc < 8; ++jc) {
        xg[jc] = *(const float4*)(xr + 4 * jc);
        tg[jc] = *(const float4*)(tr + 4 * jc);
      }
#pragma unroll
      for (int i = 0; i < RG; ++i) {
        int ra = r0 + i + 15;
        if (ra < IMG_H) { float2 v = tc2[ra * 256]; sx += v.x; sy += v.y; }
        vls[i * VST + li] = sx; vls[i * VST + li + 1] = sy;
        int rs = r0 + i - 15;
        if (rs >= 0) { float2 u = tc2[rs * 256]; sx -= u.x; sy -= u.y; }
      }
    }
  }

  __syncthreads();

  // ---- Stage 2: row prefix sums + box from registers + fused elementwise ----
  const float* vr = &vls[row * VST];
  float q[32];
  {
    const float4* rb4 = (const float4*)(vr + 36 * sub);
    float run = 0.f;
#pragma unroll
    for (int kk = 0; kk < 8; ++kk) {
      float4 vv = rb4[kk];
      q[4 * kk + 0] = run + vv.x;
      q[4 * kk + 1] = q[4 * kk + 0] + vv.y;
      q[4 * kk + 2] = q[4 * kk + 1] + vv.z;
      q[4 * kk + 3] = q[4 * kk + 2] + vv.w;
      run = q[4 * kk + 3];
    }
  }
  // segmented (width-16) inclusive scan of chunk totals across the row
  {
    float tot = q[31];
    float s = tot;
#pragma unroll
    for (int d = 1; d < 16; d <<= 1) {
      float u = __shfl_up(s, d, 64);
      if (sub >= d) s += u;
    }
    float base = s - tot;
#pragma unroll
    for (int j = 0; j < 32; ++j) q[j] += base;   // q[j] = P[c0+j]
  }

  // box[c] = P[min(c+15,511)] - (c>=16 ? P[c-16] : 0); neighbors via shfl.
  const float inv_area = 1.0f / 961.0f;
  float aW = 0.f, aWB = 0.f, aI = 0.f, aU = 0.f;
#pragma unroll
  for (int jc = 0; jc < 8; ++jc) {
    float xa[4] = {xg[jc].x, xg[jc].y, xg[jc].z, xg[jc].w};
    float ta[4] = {tg[jc].x, tg[jc].y, tg[jc].z, tg[jc].w};
#pragma unroll
    for (int e = 0; e < 4; ++e) {
      const int j = 4 * jc + e;
      float hi, lo;
      if (j <= 16) {
        hi = q[j + 15];
      } else {
        float g = __shfl_down(q[j - 17], 1);
        hi = (sub == 15) ? q[31] : g;
      }
      if (j >= 16) {
        lo = q[j - 16];
      } else {
        float g = __shfl_up(q[j + 16], 1);
        lo = (sub == 0) ? 0.f : g;
      }
      float box = hi - lo;
      float tv = ta[e], xv = xa[e];
      float w   = fmaf(5.0f, fabsf(box * inv_area - tv), 1.0f);
      float ez  = __expf(-fabsf(xv));            // single exp
      float inv = 1.0f / (1.0f + ez);
      float p   = (xv >= 0.f) ? inv : ez * inv;  // sigmoid(x)
      float bce = fmaxf(xv, 0.f) - xv * tv + __logf(1.0f + ez);
      aW  += w;
      aWB = fmaf(w, bce, aWB);
      aI  = fmaf(p * tv, w, aI);
      aU  = fmaf(p + tv, w, aU);
    }
  }

  aW  = wave_reduce(aW);
  aWB = wave_reduce(aWB);
  aI  = wave_reduce(aI);
  aU  = wave_reduce(aU);
  const int wv = tid >> 6, ln = tid & 63;
  if (ln == 0) { red[wv][0] = aW; red[wv][1] = aWB; red[wv][2] = aI; red[wv][3] = aU; }
  __syncthreads();
  if (tid < 4)
    part[(img * NGRP + grp) * 4 + tid] =
        red[0][tid] + red[1][tid] + red[2][tid] + red[3][tid];
}

// ---- finalize: reduce 1024 block-partials -> scalar loss ----
__global__ void sloss_final(const float* __restrict__ part,
                            float* __restrict__ out) {
  __shared__ float s[128];
  int tid = threadIdx.x;          // 128 threads
  int img = tid >> 2, q = tid & 3;
  float v = 0.f;
#pragma unroll 4
  for (int g = 0; g < NGRP; ++g) v += part[((img << 5) + g) * 4 + q];
  s[tid] = v;
  __syncthreads();
  float loss = 0.f;
  if (tid < NB) {
    float aW  = s[tid * 4 + 0];
    float aWB = s[tid * 4 + 1];
    float aI  = s[tid * 4 + 2];
    float aU  = s[tid * 4 + 3];
    loss = aWB / aW + 1.0f - (aI + 1.0f) / (aU - aI + 1.0f);
  }
  loss = wave_reduce(loss);
  if (tid == 0) out[0] = loss * (1.0f / (float)NB);
}

extern "C" void kernel_launch(void* const* d_in, const int* in_sizes, int n_in,
                              void* d_out, int out_size, void* d_ws, size_t ws_size,
                              hipStream_t stream) {
  const float* x = (const float*)d_in[0];
  const float* t = (const float*)d_in[1];
  float* part = (float*)d_ws;     // 1024 x 4 floats, fully overwritten

  sloss_main<<<NB * NGRP, NTH, 0, stream>>>(x, t, part);
  sloss_final<<<1, 128, 0, stream>>>(part, (float*)d_out);
}